// Round 16
// baseline (2322.845 us; speedup 1.0000x reference)
//
#include <hip/hip_runtime.h>
#include <hip/hip_bf16.h>

// Problem constants
#define BQ    8192
#define FIN   12288
#define SUN   4096
#define HIDN  1024
#define XW    2048
#define H1N   28
#define H2N   14
#define NWAY  5
#define BN_EPS 1e-5f
#define LEAKS 0.001f

typedef __bf16 bf16x8 __attribute__((ext_vector_type(8)));
typedef float  f32x4  __attribute__((ext_vector_type(4)));
typedef unsigned short ushort8 __attribute__((ext_vector_type(8)));

__device__ __forceinline__ unsigned short f2bf(float f) {
    unsigned u = __float_as_uint(f);
    unsigned r = u + 0x7fffu + ((u >> 16) & 1u);   // RNE
    return (unsigned short)(r >> 16);
}

__device__ __forceinline__ ushort8 cvt8(const float4 a, const float4 b) {
    union { __bf16 h[8]; ushort8 u; } r;
    r.h[0] = (__bf16)a.x; r.h[1] = (__bf16)a.y;
    r.h[2] = (__bf16)a.z; r.h[3] = (__bf16)a.w;
    r.h[4] = (__bf16)b.x; r.h[5] = (__bf16)b.y;
    r.h[6] = (__bf16)b.z; r.h[7] = (__bf16)b.w;
    return r.u;
}

#define TO_LDS(p) ((__attribute__((address_space(3))) void*)(p))
#define TO_GLB(p) ((const __attribute__((address_space(1))) void*)(p))

// ---------------------------------------------------------------------------
__global__ __launch_bounds__(256) void cvt_bf16(
    const float* __restrict__ in, unsigned short* __restrict__ out, long long n8)
{
    const long long idx = (long long)blockIdx.x * 256 + threadIdx.x;
    const long long stride = (long long)gridDim.x * 256;
    for (long long i = idx; i < n8; i += stride) {
        const float4 a = ((const float4*)in)[2 * i];
        const float4 b = ((const float4*)in)[2 * i + 1];
        ((ushort8*)out)[i] = cvt8(a, b);
    }
}

// ---------------------------------------------------------------------------
__global__ __launch_bounds__(256) void transpose_cvt(
    const float* __restrict__ in, unsigned short* __restrict__ out,
    int R, int Cc, const int* __restrict__ dom)
{
    if (dom) in += (size_t)(*dom) * (size_t)R * (size_t)Cc;
    __shared__ float tile[64][65];
    const int t  = threadIdx.x;
    const int tr = t >> 4;
    const int tc = t & 15;
    const int c0 = blockIdx.x * 64;
    const int r0 = blockIdx.y * 64;

    #pragma unroll
    for (int q = 0; q < 4; ++q) {
        const int r = r0 + tr + q * 16;
        const float4 v = *(const float4*)&in[(size_t)r * Cc + c0 + tc * 4];
        tile[tc*4+0][tr + q*16] = v.x;
        tile[tc*4+1][tr + q*16] = v.y;
        tile[tc*4+2][tr + q*16] = v.z;
        tile[tc*4+3][tr + q*16] = v.w;
    }
    __syncthreads();
    #pragma unroll
    for (int q = 0; q < 4; ++q) {
        const int c = c0 + tr + q * 16;
        ushort4 o;
        o.x = f2bf(tile[tr + q*16][tc*4+0]);
        o.y = f2bf(tile[tr + q*16][tc*4+1]);
        o.z = f2bf(tile[tr + q*16][tc*4+2]);
        o.w = f2bf(tile[tr + q*16][tc*4+3]);
        *(ushort4*)&out[(size_t)c * R + r0 + tc * 4] = o;
    }
}

// ---------------------------------------------------------------------------
// m97-structure bf16 MFMA GEMM (128x128, 2-barrier) — fp32-A fallback only.
// ---------------------------------------------------------------------------
template<bool A_F32, bool OUT_F32, int ACT>
__global__ __launch_bounds__(256) void gemm_mfma(
    const void* __restrict__ Ap, const unsigned short* __restrict__ Bt,
    const float* __restrict__ bias, void* __restrict__ Cp,
    int M, int N, int K, int ldc, int cc0,
    const int* __restrict__ dom, int biasStride)
{
    __shared__ alignas(16) unsigned short As[128 * 32];
    __shared__ alignas(16) unsigned short Bs[128 * 32];

    const int nbx = N >> 7;
    int wg = blockIdx.x;
    const int nwg = gridDim.x;
    if ((nwg & 7) == 0) {
        const int cpx = nwg >> 3;
        wg = (wg & 7) * cpx + (wg >> 3);
    }
    const int bx = wg % nbx, by = wg / nbx;
    const int row0 = by << 7, col0 = bx << 7;

    const int t  = threadIdx.x;
    const int w  = t >> 6;
    const int l  = t & 63;
    const int wr = w >> 1, wc = w & 1;
    const int lr = l & 15, lk = l >> 4;
    const int rsw = (lr >> 1) & 3;

    f32x4 acc[4][4];
    #pragma unroll
    for (int i = 0; i < 4; ++i)
        #pragma unroll
        for (int j = 0; j < 4; ++j)
            acc[i][j] = (f32x4)(0.f);

    const int srow = l >> 2;
    const int skb  = (((l & 3) ^ ((l >> 3) & 3)) * 16);
    const float* Af = (const float*)Ap;
    const unsigned short* Ab = (const unsigned short*)Ap;

    for (int k0 = 0; k0 < K; k0 += 32) {
        __syncthreads();

        #pragma unroll
        for (int c = 0; c < 2; ++c) {
            const int inst = w * 2 + c;
            const int row  = inst * 16 + srow;
            const char* src = (const char*)Bt +
                (((size_t)(col0 + row) * K + k0) * 2 + skb);
            char* dst = (char*)Bs + inst * 1024;
            __builtin_amdgcn_global_load_lds(TO_GLB(src), TO_LDS(dst), 16, 0, 0);
        }
        if (!A_F32) {
            #pragma unroll
            for (int c = 0; c < 2; ++c) {
                const int inst = w * 2 + c;
                const int row  = inst * 16 + srow;
                const char* src = (const char*)Ab +
                    (((size_t)(row0 + row) * K + k0) * 2 + skb);
                char* dst = (char*)As + inst * 1024;
                __builtin_amdgcn_global_load_lds(TO_GLB(src), TO_LDS(dst), 16, 0, 0);
            }
        } else {
            #pragma unroll
            for (int c = 0; c < 2; ++c) {
                const int ci  = t + 256 * c;
                const int row = ci >> 2;
                const int ko  = (((ci & 3) ^ ((ci >> 3) & 3)) * 8);
                const float* s = Af + (size_t)(row0 + row) * K + k0 + ko;
                const float4 v0 = *(const float4*)s;
                const float4 v1 = *(const float4*)(s + 4);
                *(ushort8*)&As[ci * 8] = cvt8(v0, v1);
            }
        }
        __syncthreads();

        bf16x8 af[4], bfv[4];
        #pragma unroll
        for (int i = 0; i < 4; ++i)
            af[i]  = *(const bf16x8*)&As[(wr*64 + i*16 + lr) * 32 + (lk ^ rsw) * 8];
        #pragma unroll
        for (int j = 0; j < 4; ++j)
            bfv[j] = *(const bf16x8*)&Bs[(wc*64 + j*16 + lr) * 32 + (lk ^ rsw) * 8];
        #pragma unroll
        for (int i = 0; i < 4; ++i)
            #pragma unroll
            for (int j = 0; j < 4; ++j)
                acc[i][j] = __builtin_amdgcn_mfma_f32_16x16x32_bf16(
                    af[i], bfv[j], acc[i][j], 0, 0, 0);
    }

    if (dom) bias += (*dom) * biasStride;
    const int colb = col0 + wc * 64 + lr;
    const int rowb = row0 + wr * 64 + lk * 4;
    float bj[4];
    #pragma unroll
    for (int j = 0; j < 4; ++j) bj[j] = bias[colb + j * 16];

    #pragma unroll
    for (int i = 0; i < 4; ++i) {
        #pragma unroll
        for (int r = 0; r < 4; ++r) {
            const size_t row = rowb + i * 16 + r;
            #pragma unroll
            for (int j = 0; j < 4; ++j) {
                float x = acc[i][j][r] + bj[j];
                if (ACT == 1)      x = fmaxf(x, 0.f);
                else if (ACT == 2) x = (x > 0.f) ? x : LEAKS * x;
                const size_t idx = row * (size_t)ldc + cc0 + colb + j * 16;
                if (OUT_F32) ((float*)Cp)[idx] = x;
                else         ((unsigned short*)Cp)[idx] = f2bf(x);
            }
        }
    }
}

// ---------------------------------------------------------------------------
// gemm256 (v1): kept for fallback path only.
// ---------------------------------------------------------------------------
__global__ __launch_bounds__(512, 2) void gemm256(
    const unsigned short* __restrict__ A, const unsigned short* __restrict__ Bt,
    const float* __restrict__ bias, unsigned short* __restrict__ C,
    int M, int N, int K)
{
    __shared__ alignas(16) unsigned short lds[3][2][256 * 32];  // 96 KiB

    const int nbx = N >> 8;
    int wg = blockIdx.x;
    const int nwg = gridDim.x;
    if ((nwg & 7) == 0) {
        const int cpx = nwg >> 3;
        wg = (wg & 7) * cpx + (wg >> 3);
    }
    const int bx = wg % nbx, by = wg / nbx;
    const int row0 = by << 8, col0 = bx << 8;

    const int t  = threadIdx.x;
    const int w  = t >> 6, l = t & 63;
    const int wr = w >> 2, wc = w & 3;
    const int lr = l & 15, lk = l >> 4;
    const int rsw = (lr >> 1) & 3;
    const int srow = l >> 2;
    const int skel = ((l & 3) ^ ((l >> 3) & 3)) * 8;

    f32x4 acc[8][4];
    #pragma unroll
    for (int i = 0; i < 8; ++i)
        #pragma unroll
        for (int j = 0; j < 4; ++j)
            acc[i][j] = (f32x4)(0.f);

    const int NT = K >> 5;

    #define STAGE256(tile_)  do {                                            \
        const int k0_  = (tile_) << 5;                                       \
        const int buf_ = (tile_) % 3;                                        \
        _Pragma("unroll")                                                    \
        for (int s_ = 0; s_ < 2; ++s_) {                                     \
            const int c_   = w * 2 + s_;                                     \
            const int row_ = c_ * 16 + srow;                                 \
            __builtin_amdgcn_global_load_lds(                                \
                TO_GLB(A + (size_t)(row0 + row_) * K + k0_ + skel),          \
                TO_LDS((char*)&lds[buf_][0][0] + c_ * 1024), 16, 0, 0);      \
            __builtin_amdgcn_global_load_lds(                                \
                TO_GLB(Bt + (size_t)(col0 + row_) * K + k0_ + skel),         \
                TO_LDS((char*)&lds[buf_][1][0] + c_ * 1024), 16, 0, 0);      \
        }                                                                    \
    } while (0)

    STAGE256(0);
    if (NT > 1) {
        STAGE256(1);
        asm volatile("s_waitcnt vmcnt(4)" ::: "memory");
    } else {
        asm volatile("s_waitcnt vmcnt(0)" ::: "memory");
    }
    __builtin_amdgcn_sched_barrier(0);
    __builtin_amdgcn_s_barrier();
    __builtin_amdgcn_sched_barrier(0);

    for (int tt = 0; tt < NT; ++tt) {
        const int buf = tt % 3;
        if (tt + 2 < NT) STAGE256(tt + 2);
        __builtin_amdgcn_sched_barrier(0);

        bf16x8 af[8], bfv[4];
        #pragma unroll
        for (int i = 0; i < 8; ++i)
            af[i]  = *(const bf16x8*)&lds[buf][0][(wr*128 + i*16 + lr) * 32 + (lk ^ rsw) * 8];
        #pragma unroll
        for (int j = 0; j < 4; ++j)
            bfv[j] = *(const bf16x8*)&lds[buf][1][(wc*64 + j*16 + lr) * 32 + (lk ^ rsw) * 8];

        __builtin_amdgcn_s_setprio(1);
        #pragma unroll
        for (int j = 0; j < 4; ++j)
            #pragma unroll
            for (int i = 0; i < 8; ++i)
                acc[i][j] = __builtin_amdgcn_mfma_f32_16x16x32_bf16(
                    af[i], bfv[j], acc[i][j], 0, 0, 0);
        __builtin_amdgcn_s_setprio(0);

        if (tt + 1 < NT) {
            if (tt + 2 < NT) asm volatile("s_waitcnt vmcnt(4)" ::: "memory");
            else             asm volatile("s_waitcnt vmcnt(0)" ::: "memory");
            __builtin_amdgcn_sched_barrier(0);
            __builtin_amdgcn_s_barrier();
            __builtin_amdgcn_sched_barrier(0);
        }
    }
    #undef STAGE256

    const int colb = col0 + wc * 64 + lr;
    const int rowb = row0 + wr * 128 + lk * 4;
    float bj[4];
    #pragma unroll
    for (int j = 0; j < 4; ++j) bj[j] = bias[colb + j * 16];

    #pragma unroll
    for (int i = 0; i < 8; ++i) {
        #pragma unroll
        for (int r = 0; r < 4; ++r) {
            const size_t row = rowb + i * 16 + r;
            #pragma unroll
            for (int j = 0; j < 4; ++j) {
                float x = fmaxf(acc[i][j][r] + bj[j], 0.f);
                C[row * (size_t)N + colb + j * 16] = f2bf(x);
            }
        }
    }
}

// ---------------------------------------------------------------------------
// gemm256_8ph — 8-phase schedule.
// MODE 0: 2 barriers/phase + lgkmcnt pin   [R11/R12-proven]
// MODE 1: 1 barrier/phase + lgkmcnt pin    [R14/R15-proven best]
// MODE 2: 1 barrier/phase, no explicit pins (compiler fine-grained lgkmcnt)
// Race ledger identical for all modes (PH_END s_barrier placement unchanged;
// memory ops don't cross s_barrier; same-wave read->MFMA deps are
// compiler-tracked). Accumulation k-ascending -> bit-identical output
// (absmax canary 0.0005531311). Requires M,N % 256 == 0, K % 128 == 0.
// ---------------------------------------------------------------------------
template<int MODE>
__global__ __launch_bounds__(512, 2) void gemm256_8ph(
    const unsigned short* __restrict__ A, const unsigned short* __restrict__ Bt,
    const float* __restrict__ bias, unsigned short* __restrict__ C,
    int M, int N, int K)
{
    __shared__ alignas(16) unsigned short lds[2][2][2][128 * 64];  // 128 KiB

    const int nbx = N >> 8;
    int wg = blockIdx.x;
    const int nwg = gridDim.x;
    if ((nwg & 7) == 0) { const int cpx = nwg >> 3; wg = (wg & 7) * cpx + (wg >> 3); }
    const int bx = wg % nbx, by = wg / nbx;
    const int row0 = by << 8, col0 = bx << 8;

    const int t = threadIdx.x;
    const int w = t >> 6, l = t & 63;
    const int wr = w >> 2, wc = w & 3;
    const int lr = l & 15, lk = l >> 4;

    f32x4 acc[8][4];
    #pragma unroll
    for (int i = 0; i < 8; ++i)
        #pragma unroll
        for (int j = 0; j < 4; ++j) acc[i][j] = (f32x4)(0.f);

    const int NT = K >> 6;     // K-tiles of 64 (even; >=2)
    const int NI = NT >> 1;

    #define STG(mat_, kt_, h_) do {                                              \
        const unsigned short* gb_ = (mat_) ? Bt : A;                              \
        const int gr0_ = (mat_) ? col0 : row0;                                    \
        _Pragma("unroll")                                                         \
        for (int s_ = 0; s_ < 2; ++s_) {                                          \
            const int c_   = s_ * 8 + w;                                          \
            const int row_ = c_ * 8 + (l >> 3);                                   \
            const int g_   = (l & 7) ^ (row_ & 7);                                \
            __builtin_amdgcn_global_load_lds(                                     \
                TO_GLB(gb_ + (size_t)(gr0_ + (h_) * 128 + row_) * K + (kt_) * 64 + g_ * 8), \
                TO_LDS((char*)&lds[mat_][(kt_) & 1][h_][0] + c_ * 1024), 16, 0, 0);\
        } } while (0)

    #define RD_A(dst_, buf_, qi_) do {                                            \
        _Pragma("unroll")                                                         \
        for (int ks_ = 0; ks_ < 2; ++ks_)                                         \
        _Pragma("unroll")                                                         \
        for (int ii_ = 0; ii_ < 4; ++ii_) {                                       \
            const int rh_ = wr * 64 + ii_ * 16 + lr;                              \
            dst_[ks_][ii_] = *(const bf16x8*)                                     \
                &lds[0][buf_][qi_][rh_ * 64 + (((ks_ * 4 + lk) ^ (rh_ & 7)) << 3)]; \
        } } while (0)

    #define RD_B(dst_, buf_, qj_) do {                                            \
        _Pragma("unroll")                                                         \
        for (int ks_ = 0; ks_ < 2; ++ks_)                                         \
        _Pragma("unroll")                                                         \
        for (int jj_ = 0; jj_ < 2; ++jj_) {                                       \
            const int rh_ = wc * 32 + jj_ * 16 + lr;                              \
            dst_[ks_][jj_] = *(const bf16x8*)                                     \
                &lds[1][buf_][qj_][rh_ * 64 + (((ks_ * 4 + lk) ^ (rh_ & 7)) << 3)]; \
        } } while (0)

    #define SYNC_IN() do {                                                        \
        if (MODE == 0) {                                                          \
            __builtin_amdgcn_sched_barrier(0);                                    \
            __builtin_amdgcn_s_barrier();                                         \
        }                                                                         \
        if (MODE <= 1) {                                                          \
            asm volatile("s_waitcnt lgkmcnt(0)" ::: "memory");                    \
            __builtin_amdgcn_sched_barrier(0);                                    \
        } } while (0)

    #define MFMA16(aa_, bb_, qi_, qj_) do {                                       \
        __builtin_amdgcn_s_setprio(1);                                            \
        _Pragma("unroll")                                                         \
        for (int ks_ = 0; ks_ < 2; ++ks_)                                         \
        _Pragma("unroll")                                                         \
        for (int jj_ = 0; jj_ < 2; ++jj_)                                         \
        _Pragma("unroll")                                                         \
        for (int ii_ = 0; ii_ < 4; ++ii_)                                         \
            acc[(qi_)*4+ii_][(qj_)*2+jj_] = __builtin_amdgcn_mfma_f32_16x16x32_bf16( \
                aa_[ks_][ii_], bb_[ks_][jj_], acc[(qi_)*4+ii_][(qj_)*2+jj_], 0, 0, 0); \
        __builtin_amdgcn_s_setprio(0); } while (0)

    #define PH_END() do {                                                         \
        __builtin_amdgcn_sched_barrier(0);                                        \
        __builtin_amdgcn_s_barrier(); } while (0)

    // prologue: t0 full + t1.A0/B0 (6 halves); retire t0 (keep 4 loads)
    STG(0, 0, 0); STG(0, 0, 1); STG(1, 0, 0); STG(1, 0, 1);
    STG(0, 1, 0); STG(1, 1, 0);
    asm volatile("s_waitcnt vmcnt(4)" ::: "memory");
    __builtin_amdgcn_sched_barrier(0);
    __builtin_amdgcn_s_barrier();
    __builtin_amdgcn_sched_barrier(0);

    for (int m = 0; m < NI; ++m) {
        const int t1 = 2 * m + 1, u0 = 2 * m + 2, u1 = 2 * m + 3;
        const bool last = (m == NI - 1);
        bf16x8 a_[2][4], b0_[2][2], b1_[2][2];

        // ph1: t0 q(0,0)
        RD_A(a_, 0, 0); RD_B(b0_, 0, 0);
        STG(0, t1, 1);
        SYNC_IN(); MFMA16(a_, b0_, 0, 0); PH_END();
        // ph2: t0 q(0,1)
        RD_B(b1_, 0, 1);
        STG(1, t1, 1);
        SYNC_IN(); MFMA16(a_, b1_, 0, 1); PH_END();
        // ph3: t0 q(1,0)
        RD_A(a_, 0, 1);
        if (u0 < NT) STG(0, u0, 0);
        SYNC_IN(); MFMA16(a_, b0_, 1, 0); PH_END();
        // ph4: t0 q(1,1) + K-tile wait
        if (u0 < NT) STG(1, u0, 0);
        SYNC_IN(); MFMA16(a_, b1_, 1, 1);
        if (last) asm volatile("s_waitcnt vmcnt(0)" ::: "memory");
        else      asm volatile("s_waitcnt vmcnt(4)" ::: "memory");
        PH_END();
        // ph5: t1 q(0,0)
        RD_A(a_, 1, 0); RD_B(b0_, 1, 0);
        if (u0 < NT) STG(0, u0, 1);
        SYNC_IN(); MFMA16(a_, b0_, 0, 0); PH_END();
        // ph6: t1 q(0,1)
        RD_B(b1_, 1, 1);
        if (u0 < NT) STG(1, u0, 1);
        SYNC_IN(); MFMA16(a_, b1_, 0, 1); PH_END();
        // ph7: t1 q(1,0)
        RD_A(a_, 1, 1);
        if (u1 < NT) STG(0, u1, 0);
        SYNC_IN(); MFMA16(a_, b0_, 1, 0); PH_END();
        // ph8: t1 q(1,1) + K-tile wait
        if (u1 < NT) STG(1, u1, 0);
        SYNC_IN(); MFMA16(a_, b1_, 1, 1);
        if (!last) asm volatile("s_waitcnt vmcnt(4)" ::: "memory");
        PH_END();
    }
    #undef STG
    #undef RD_A
    #undef RD_B
    #undef SYNC_IN
    #undef MFMA16
    #undef PH_END

    const int colb = col0 + wc * 32 + lr;
    const int rowb = row0 + wr * 64 + lk * 4;
    float bj[4];
    #pragma unroll
    for (int j = 0; j < 4; ++j)
        bj[j] = bias[colb + (j >> 1) * 128 + (j & 1) * 16];

    #pragma unroll
    for (int i = 0; i < 8; ++i) {
        const int gri = rowb + (i >> 2) * 128 + (i & 3) * 16;
        #pragma unroll
        for (int r = 0; r < 4; ++r) {
            const size_t row = gri + r;
            #pragma unroll
            for (int j = 0; j < 4; ++j) {
                float x = fmaxf(acc[i][j][r] + bj[j], 0.f);
                C[row * (size_t)N + colb + (j >> 1) * 128 + (j & 1) * 16] = f2bf(x);
            }
        }
    }
}

// ---------------------------------------------------------------------------
// gemm128: proven pipeline at 128x128 / 4 waves / 48 KiB. Narrow-N GEMMs 6/7.
// ---------------------------------------------------------------------------
template<bool OUT_F32, int ACT>
__global__ __launch_bounds__(256, 2) void gemm128(
    const unsigned short* __restrict__ A, const unsigned short* __restrict__ Bt,
    const float* __restrict__ bias, void* __restrict__ Cp,
    int M, int N, int K, int ldc, int cc0,
    const int* __restrict__ dom, int biasStride)
{
    __shared__ alignas(16) unsigned short lds[3][2][128 * 32];  // 48 KiB

    const int nbx = N >> 7;
    int wg = blockIdx.x;
    const int nwg = gridDim.x;
    if ((nwg & 7) == 0) {
        const int cpx = nwg >> 3;
        wg = (wg & 7) * cpx + (wg >> 3);
    }
    const int bx = wg % nbx, by = wg / nbx;
    const int row0 = by << 7, col0 = bx << 7;

    const int t  = threadIdx.x;
    const int w  = t >> 6, l = t & 63;
    const int wr = w >> 1, wc = w & 1;
    const int lr = l & 15, lk = l >> 4;
    const int rsw = (lr >> 1) & 3;
    const int srow = l >> 2;
    const int skel = ((l & 3) ^ ((l >> 3) & 3)) * 8;

    f32x4 acc[4][4];
    #pragma unroll
    for (int i = 0; i < 4; ++i)
        #pragma unroll
        for (int j = 0; j < 4; ++j)
            acc[i][j] = (f32x4)(0.f);

    const int NT = K >> 5;

    #define STAGE128(tile_)  do {                                            \
        const int k0_  = (tile_) << 5;                                       \
        const int buf_ = (tile_) % 3;                                        \
        _Pragma("unroll")                                                    \
        for (int s_ = 0; s_ < 2; ++s_) {                                     \
            const int c_   = w * 2 + s_;                                     \
            const int row_ = c_ * 16 + srow;                                 \
            __builtin_amdgcn_global_load_lds(                                \
                TO_GLB(A + (size_t)(row0 + row_) * K + k0_ + skel),          \
                TO_LDS((char*)&lds[buf_][0][0] + c_ * 1024), 16, 0, 0);      \
            __builtin_amdgcn_global_load_lds(                                \
                TO_GLB(Bt + (size_t)(col0 + row_) * K + k0_ + skel),         \
                TO_LDS((char*)&lds[buf_][1][0] + c_ * 1024), 16, 0, 0);      \
        }                                                                    \
    } while (0)

    STAGE128(0);
    if (NT > 1) {
        STAGE128(1);
        asm volatile("s_waitcnt vmcnt(4)" ::: "memory");
    } else {
        asm volatile("s_waitcnt vmcnt(0)" ::: "memory");
    }
    __builtin_amdgcn_sched_barrier(0);
    __builtin_amdgcn_s_barrier();
    __builtin_amdgcn_sched_barrier(0);

    for (int tt = 0; tt < NT; ++tt) {
        const int buf = tt % 3;
        if (tt + 2 < NT) STAGE128(tt + 2);
        __builtin_amdgcn_sched_barrier(0);

        bf16x8 af[4], bfv[4];
        #pragma unroll
        for (int i = 0; i < 4; ++i)
            af[i]  = *(const bf16x8*)&lds[buf][0][(wr*64 + i*16 + lr) * 32 + (lk ^ rsw) * 8];
        #pragma unroll
        for (int j = 0; j < 4; ++j)
            bfv[j] = *(const bf16x8*)&lds[buf][1][(wc*64 + j*16 + lr) * 32 + (lk ^ rsw) * 8];

        #pragma unroll
        for (int j = 0; j < 4; ++j)
            #pragma unroll
            for (int i = 0; i < 4; ++i)
                acc[i][j] = __builtin_amdgcn_mfma_f32_16x16x32_bf16(
                    af[i], bfv[j], acc[i][j], 0, 0, 0);

        if (tt + 1 < NT) {
            if (tt + 2 < NT) asm volatile("s_waitcnt vmcnt(4)" ::: "memory");
            else             asm volatile("s_waitcnt vmcnt(0)" ::: "memory");
            __builtin_amdgcn_sched_barrier(0);
            __builtin_amdgcn_s_barrier();
            __builtin_amdgcn_sched_barrier(0);
        }
    }
    #undef STAGE128

    if (dom) bias += (*dom) * biasStride;
    const int colb = col0 + wc * 64 + lr;
    const int rowb = row0 + wr * 64 + lk * 4;
    float bj[4];
    #pragma unroll
    for (int j = 0; j < 4; ++j) bj[j] = bias[colb + j * 16];

    #pragma unroll
    for (int i = 0; i < 4; ++i) {
        #pragma unroll
        for (int r = 0; r < 4; ++r) {
            const size_t row = rowb + i * 16 + r;
            #pragma unroll
            for (int j = 0; j < 4; ++j) {
                float x = acc[i][j][r] + bj[j];
                if (ACT == 1)      x = fmaxf(x, 0.f);
                else if (ACT == 2) x = (x > 0.f) ? x : LEAKS * x;
                const size_t idx = row * (size_t)ldc + cc0 + colb + j * 16;
                if (OUT_F32) ((float*)Cp)[idx] = x;
                else         ((unsigned short*)Cp)[idx] = f2bf(x);
            }
        }
    }
}

// ---------------------------------------------------------------------------
// BatchNorm stats + heads — unchanged (proven).
// ---------------------------------------------------------------------------
__global__ __launch_bounds__(256) void bn_stats_a(
    const float* __restrict__ X, float* __restrict__ psum, float* __restrict__ pss)
{
    const int c  = blockIdx.x * 256 + threadIdx.x;
    const int rb = blockIdx.y;
    float s = 0.f, ss = 0.f;
    const int r0 = rb * 256;
    for (int r = r0; r < r0 + 256; ++r) {
        float v = X[(size_t)r * XW + c];
        s += v; ss = fmaf(v, v, ss);
    }
    psum[rb * XW + c] = s;
    pss [rb * XW + c] = ss;
}

__global__ __launch_bounds__(256) void bn_stats_b(
    const float* __restrict__ psum, const float* __restrict__ pss,
    const float* __restrict__ gamma, const float* __restrict__ beta,
    float* __restrict__ scale, float* __restrict__ shift)
{
    const int c = blockIdx.x * 256 + threadIdx.x;
    float s = 0.f, ss = 0.f;
    for (int rb = 0; rb < 32; ++rb) { s += psum[rb * XW + c]; ss += pss[rb * XW + c]; }
    const float inv = 1.f / (float)BQ;
    const float mean = s * inv;
    const float var  = ss * inv - mean * mean;
    const float sc = gamma[c] * rsqrtf(var + BN_EPS);
    scale[c] = sc;
    shift[c] = beta[c] - mean * sc;
}

__global__ __launch_bounds__(256) void head_kernel(
    const float* __restrict__ X, const float* __restrict__ scale,
    const float* __restrict__ shift, const int* __restrict__ tt,
    const float* __restrict__ Wh1, const float* __restrict__ bh1,
    const float* __restrict__ Wh2, const float* __restrict__ bh2,
    const float* __restrict__ Wh3, const float* __restrict__ bh3,
    float* __restrict__ out)
{
    __shared__ float xs[4][XW];
    __shared__ float y1[4][H1N];
    __shared__ float y2[4][H2N + 2];

    const int t = threadIdx.x;
    const int w = t >> 6;
    const int l = t & 63;
    const int s = blockIdx.x * 4 + w;
    const int d = tt[s];

    #pragma unroll 4
    for (int i = 0; i < XW / 64; ++i) {
        const int c = i * 64 + l;
        xs[w][c] = fmaf(X[(size_t)s * XW + c], scale[c], shift[c]);
    }
    __syncthreads();

    if (l < H1N) {
        const float* W1 = Wh1 + (size_t)d * XW * H1N;
        float acc = bh1[d * H1N + l];
        #pragma unroll 8
        for (int c = 0; c < XW; ++c)
            acc = fmaf(xs[w][c], W1[c * H1N + l], acc);
        y1[w][l] = fmaxf(acc, 0.f);
    }
    __syncthreads();

    if (l < H2N) {
        const float* W2 = Wh2 + (size_t)d * H1N * H2N;
        float acc = bh2[d * H2N + l];
        #pragma unroll
        for (int c = 0; c < H1N; ++c)
            acc = fmaf(y1[w][c], W2[c * H2N + l], acc);
        y2[w][l] = fmaxf(acc, 0.f);
    }
    __syncthreads();

    if (l < NWAY) {
        const float* W3 = Wh3 + (size_t)d * H2N * NWAY;
        float acc = bh3[d * NWAY + l];
        #pragma unroll
        for (int c = 0; c < H2N; ++c)
            acc = fmaf(y2[w][c], W3[c * NWAY + l], acc);
        out[(size_t)s * NWAY + l] = acc;
    }
}

// ---------------------------------------------------------------------------
extern "C" void kernel_launch(void* const* d_in, const int* in_sizes, int n_in,
                              void* d_out, int out_size, void* d_ws, size_t ws_size,
                              hipStream_t stream)
{
    const float* x_s   = (const float*)d_in[0];
    const float* x_p   = (const float*)d_in[1];
    const int*   tt    = (const int*)  d_in[2];
    const int*   dom   = (const int*)  d_in[3];
    const float* W_in  = (const float*)d_in[4];
    const float* b_in  = (const float*)d_in[5];
    const float* W_hid = (const float*)d_in[6];
    const float* b_hid = (const float*)d_in[7];
    const float* W_out = (const float*)d_in[8];
    const float* b_out = (const float*)d_in[9];
    const float* Wp    = (const float*)d_in[10];
    const float* bp    = (const float*)d_in[11];
    const float* gamma = (const float*)d_in[12];
    const float* beta  = (const float*)d_in[13];
    const float* Wh1   = (const float*)d_in[14];
    const float* bh1   = (const float*)d_in[15];
    const float* Wh2   = (const float*)d_in[16];
    const float* bh2   = (const float*)d_in[17];
    const float* Wh3   = (const float*)d_in[18];
    const float* bh3   = (const float*)d_in[19];
    float* out = (float*)d_out;

    const dim3 blk(256);
    char* w = (char*)d_ws;

    const size_t FAST_NEED = 470810624ull;

    if (ws_size >= FAST_NEED) {
        unsigned short* xb    = (unsigned short*)w;                    // 192M
        unsigned short* WinT  = (unsigned short*)(w + 201326592);      // 96M region
        unsigned short* WoutT = (unsigned short*)(w + 201326592);      //  8M
        unsigned short* WpT   = (unsigned short*)(w + 209715200);      // 24M
        unsigned short* actA  = (unsigned short*)(w + 301989888);      // 64M
        unsigned short* actB  = (unsigned short*)(w + 369098752);      // 64M
        float*          X     = (float*)(w + 369098752);               // aliases actB
        unsigned short* WhidT = (unsigned short*)(w + 436207616);      // 32M
        float*          psum  = (float*)(w + 469762048);
        float*          pss   = psum + 32 * XW;
        float*          scale = pss  + 32 * XW;
        float*          shift = scale + XW;

        cvt_bf16<<<dim3(2048), blk, 0, stream>>>(x_s, xb, (long long)BQ * FIN / 8);
        transpose_cvt<<<dim3(SUN/64,  FIN/64), blk, 0, stream>>>(W_in,  WinT,  FIN, SUN,  nullptr);
        transpose_cvt<<<dim3(SUN/64,  SUN/64), blk, 0, stream>>>(W_hid, WhidT, SUN, SUN,  nullptr);

        // GEMM1 — MODE 2 probe (A/B vs R15's MODE-1 ~666 us; long-K resolves
        // per-phase deltas 3x better than hidden layers)
        gemm256_8ph<2><<<dim3(512), dim3(512), 0, stream>>>(xb, WinT, b_in, actA, BQ, SUN, FIN);

        transpose_cvt<<<dim3(HIDN/64, SUN/64), blk, 0, stream>>>(W_out, WoutT, SUN, HIDN, nullptr);
        transpose_cvt<<<dim3(HIDN/64, FIN/64), blk, 0, stream>>>(Wp,    WpT,   FIN, HIDN, dom);
        cvt_bf16<<<dim3(2048), blk, 0, stream>>>(x_p, xb, (long long)BQ * FIN / 8);

        // hidden layers — locked to proven MODE 1
        gemm256_8ph<1><<<dim3(512), dim3(512), 0, stream>>>(actA, WhidT, b_hid, actB, BQ, SUN, SUN);
        gemm256_8ph<1><<<dim3(512), dim3(512), 0, stream>>>(actB, WhidT, b_hid, actA, BQ, SUN, SUN);
        gemm256_8ph<1><<<dim3(512), dim3(512), 0, stream>>>(actA, WhidT, b_hid, actB, BQ, SUN, SUN);
        gemm256_8ph<1><<<dim3(512), dim3(512), 0, stream>>>(actB, WhidT, b_hid, actA, BQ, SUN, SUN);

        gemm128<true,1><<<dim3(512), blk, 0, stream>>>(
            actA, WoutT, b_out, X, BQ, HIDN, SUN, XW, 0, nullptr, 0);
        gemm128<true,2><<<dim3(512), blk, 0, stream>>>(
            xb, WpT, bp, X, BQ, HIDN, FIN, XW, HIDN, dom, HIDN);

        bn_stats_a<<<dim3(XW/256, 32), blk, 0, stream>>>(X, psum, pss);
        bn_stats_b<<<dim3(XW/256),     blk, 0, stream>>>(psum, pss, gamma, beta, scale, shift);
        head_kernel<<<dim3(BQ/4), blk, 0, stream>>>(X, scale, shift, tt,
                                                    Wh1, bh1, Wh2, bh2, Wh3, bh3, out);
        return;
    }

    // ---------------- fallback: 256 MiB path ----------------
    unsigned short* actA  = (unsigned short*)w;
    unsigned short* actB  = (unsigned short*)(w + 67108864);
    float*          X     = (float*)(w + 67108864);
    unsigned short* WinT  = (unsigned short*)(w + 134217728);
    unsigned short* WoutT = (unsigned short*)(w + 134217728);
    unsigned short* WpT   = (unsigned short*)(w + 142606336);
    float*          psum  = (float*)(w + 167772160);
    float*          pss   = psum + 32 * XW;
    float*          scale = pss  + 32 * XW;
    float*          shift = scale + XW;
    unsigned short* WhidT = (unsigned short*)(w + 234881024);

    transpose_cvt<<<dim3(SUN/64,  FIN/64), blk, 0, stream>>>(W_in,  WinT,  FIN, SUN,  nullptr);
    transpose_cvt<<<dim3(SUN/64,  SUN/64), blk, 0, stream>>>(W_hid, WhidT, SUN, SUN,  nullptr);

    gemm_mfma<true,false,1><<<dim3(2048), blk, 0, stream>>>(
        x_s, WinT, b_in, actA, BQ, SUN, FIN, SUN, 0, nullptr, 0);

    transpose_cvt<<<dim3(HIDN/64, SUN/64), blk, 0, stream>>>(W_out, WoutT, SUN, HIDN, nullptr);
    transpose_cvt<<<dim3(HIDN/64, FIN/64), blk, 0, stream>>>(Wp,    WpT,   FIN, HIDN, dom);

    gemm256<<<dim3(512), dim3(512), 0, stream>>>(actA, WhidT, b_hid, actB, BQ, SUN, SUN);
    gemm256<<<dim3(512), dim3(512), 0, stream>>>(actB, WhidT, b_hid, actA, BQ, SUN, SUN);
    gemm256<<<dim3(512), dim3(512), 0, stream>>>(actA, WhidT, b_hid, actB, BQ, SUN, SUN);
    gemm256<<<dim3(512), dim3(512), 0, stream>>>(actB, WhidT, b_hid, actA, BQ, SUN, SUN);

    gemm128<true,1><<<dim3(512), blk, 0, stream>>>(
        actA, WoutT, b_out, X, BQ, HIDN, SUN, XW, 0, nullptr, 0);
    gemm_mfma<true,true,2><<<dim3(512), blk, 0, stream>>>(
        x_p, WpT, bp, X, BQ, HIDN, FIN, XW, HIDN, dom, HIDN);

    bn_stats_a<<<dim3(XW/256, 32), blk, 0, stream>>>(X, psum, pss);
    bn_stats_b<<<dim3(XW/256),     blk, 0, stream>>>(psum, pss, gamma, beta, scale, shift);
    head_kernel<<<dim3(BQ/4), blk, 0, stream>>>(X, scale, shift, tt,
                                                Wh1, bh1, Wh2, bh2, Wh3, bh3, out);
}